// Round 9
// baseline (534.492 us; speedup 1.0000x reference)
//
#include <hip/hip_runtime.h>
#include <math.h>

#define T_SEQ  512
#define HID    128
#define G3     384   // 3*HID, gate order r,z,n
#define NL     4
#define CHUNK  8
#define NCHUNK (T_SEQ / CHUNK)   // 64

// workspace layout (float offsets)
#define GI_TOT   (NL * T_SEQ * G3)
#define SEQ_TOT  (NL * T_SEQ * HID)
#define FLAG_OFF (GI_TOT + SEQ_TOT)

// Padded LDS segment layout: value k lives at (k>>5)*40 + (k&31).
// The 4 K-quarter segments start 40 floats (=8 banks) apart, so the 4
// broadcast addresses of a quad-decomposed b128 read touch disjoint banks.
#define SEGSTRIDE 40
#define HBUF      160   // 4*SEGSTRIDE

__device__ __forceinline__ float fsig(float x) {
    float e = __expf(-x);
    return 1.0f / (1.0f + e);
}
__device__ __forceinline__ float ftanh(float x) {
    float ax = fabsf(x);
    float e = __expf(-2.0f * ax);
    float t = (1.0f - e) / (1.0f + e);
    return copysignf(t, x);
}

// Handoff protocol (invalidate-free, stale-proof):
//  - writer: normal stores; __syncthreads() (drains vmcnt -> stores in XCD L2);
//    RELEASE agent atomic flag store (writes back L2 -> data at LLC before flag).
//  - reader: spins with RELAXED agent atomic fetch_add(0). An RMW executes at
//    the coherence point every poll: no buffer_inv (R4-R6's 5.5x refetch), and
//    no stale-cached-line stall (R8's 35 ms outlier from a plain relaxed load).
//    Data loads are plain: first-touch within the dispatch; dispatch boundary
//    invalidates caches between graph replays.

// ---------------- init: reset handoff flags ----------------
__global__ void init_flags(int* fl) {
    int i = threadIdx.x;
    if (i < 8) fl[i * 16] = (i == 0) ? NCHUNK : 0;  // gi0 fully ready
}

// ---------------- layer-0 gi ----------------
__global__ void gi0_kernel(const float* __restrict__ x, const float* __restrict__ Wih0,
                           const float* __restrict__ bih, float* __restrict__ gi) {
    int t = blockIdx.x;
    int g = threadIdx.x;
    float x0 = x[t * 2048 + 1023];
    float x1 = x[t * 2048 + 1024 + 1023];
    gi[t * G3 + g] = bih[g] + Wih0[g * 2 + 0] * x0 + Wih0[g * 2 + 1] * x1;
}

// ---------------- persistent pipeline: 7 blocks x 512 threads ----------------
// bid 0,2,4,6 -> rec layer bid/2 ; bid 1,3,5 -> gi layer (bid+1)/2
// Quad-owner decomposition: j = tid>>2 (output 0..127), kq = tid&3 (K-quarter).
// Thread computes gates r,z,n of j over K[kq*32..+32) (w[3][32], 96 FMAs),
// quad-reduces via __shfl_xor(1|2) (bit-identical on all 4 lanes: fp add
// commutes), gates computed redundantly, lane kq==(j>>5) writes h.
// -> ONE barrier/step, no LDS partial matrix, 8 waves (2/SIMD) for TLP.
__global__ __launch_bounds__(512, 1) void pipe_kernel(float* __restrict__ ws,
                                                      const float* __restrict__ WihR,
                                                      const float* __restrict__ bih,
                                                      const float* __restrict__ Whh,
                                                      const float* __restrict__ bhh) {
    __shared__ float smem[1408];

    int bid = blockIdx.x;
    int tid = threadIdx.x;
    int j   = tid >> 2;     // output index 0..127
    int kq  = tid & 3;      // K-quarter
    int* fl = (int*)(ws + FLAG_OFF);
    bool is_rec = (bid & 1) == 0;
    int  l      = is_rec ? (bid >> 1) : ((bid + 1) >> 1);

    if (is_rec) {
        // ---------------- rec role: layer l ----------------
        float* h_s  = smem;           // [2*HBUF] double-buffered padded h
        float* hist = smem + 2*HBUF;  // [1024] chunk history
        const float* W   = Whh + (size_t)l * G3 * HID;
        const float* gi  = ws + (size_t)l * T_SEQ * G3;
        float* seq_o     = ws + GI_TOT + (size_t)l * T_SEQ * HID;
        int* in_flag     = &fl[l * 16];
        int* out_flag    = &fl[(4 + l) * 16];

        // w[r][.] = W row (r*128 + j), cols kq*32..+31
        float w[3][32];
#pragma unroll
        for (int r = 0; r < 3; r++) {
            const float4* wr = reinterpret_cast<const float4*>(
                W + (size_t)(r * HID + j) * HID + kq * 32);
#pragma unroll
            for (int c = 0; c < 8; c++) {
                float4 v = wr[c];
                w[r][c * 4 + 0] = v.x; w[r][c * 4 + 1] = v.y;
                w[r][c * 4 + 2] = v.z; w[r][c * 4 + 3] = v.w;
            }
        }
        const float* bb = bhh + (size_t)l * G3;
        float br = bb[j], bz = bb[HID + j], bn = bb[2 * HID + j];

        float hprev = 0.0f;
        float gir = 0.f, giz = 0.f, gin = 0.f;
        float n_gir = 0.f, n_giz = 0.f, n_gin = 0.f;
        int wseg = j >> 5;            // this j's segment
        bool writer = (kq == wseg);
        if (tid < HBUF) h_s[tid] = 0.0f;   // zero buffer 0 (incl. padding)
        __syncthreads();

        for (int c = 0; c < NCHUNK; c++) {
            if (tid == 0) {
                while (__hip_atomic_fetch_add(in_flag, 0, __ATOMIC_RELAXED, __HIP_MEMORY_SCOPE_AGENT) < c + 1)
                    __builtin_amdgcn_s_sleep(2);
            }
            __syncthreads();
            int t0 = c * CHUNK;
            {   // first-step gi load
                const float* gp = gi + (size_t)t0 * G3;
                gir = gp[j]; giz = gp[HID + j]; gin = gp[2 * HID + j];
            }
            for (int s = 0; s < CHUNK; s++) {
                int t = t0 + s;
                if (s + 1 < CHUNK) {   // prefetch next gi under the matvec
                    const float* gp = gi + (size_t)(t + 1) * G3;
                    n_gir = gp[j]; n_giz = gp[HID + j]; n_gin = gp[2 * HID + j];
                }
                // matvec: 3 gates x 32 K from padded segment kq
                const float4* h4 = reinterpret_cast<const float4*>(
                    h_s + (t & 1) * HBUF + kq * SEGSTRIDE);
                float ar = 0.f, az = 0.f, an = 0.f;
#pragma unroll
                for (int cc = 0; cc < 8; cc++) {
                    float4 hv = h4[cc];
                    ar += w[0][cc*4+0]*hv.x + w[0][cc*4+1]*hv.y + w[0][cc*4+2]*hv.z + w[0][cc*4+3]*hv.w;
                    az += w[1][cc*4+0]*hv.x + w[1][cc*4+1]*hv.y + w[1][cc*4+2]*hv.z + w[1][cc*4+3]*hv.w;
                    an += w[2][cc*4+0]*hv.x + w[2][cc*4+1]*hv.y + w[2][cc*4+2]*hv.z + w[2][cc*4+3]*hv.w;
                }
                // quad reduce: ((q0+q1)+(q2+q3)), bit-identical on all 4 lanes
                ar += __shfl_xor(ar, 1, 64);  az += __shfl_xor(az, 1, 64);  an += __shfl_xor(an, 1, 64);
                ar += __shfl_xor(ar, 2, 64);  az += __shfl_xor(az, 2, 64);  an += __shfl_xor(an, 2, 64);
                float r_ = fsig(gir + ar + br);
                float z_ = fsig(giz + az + bz);
                float n_ = ftanh(gin + r_ * (an + bn));
                float hn = (1.0f - z_) * n_ + z_ * hprev;
                hprev = hn;
                if (writer) {
                    h_s[((t + 1) & 1) * HBUF + wseg * SEGSTRIDE + (j & 31)] = hn;
                    hist[s * HID + j] = hn;
                }
                gir = n_gir; giz = n_giz; gin = n_gin;
                __syncthreads();
            }
            // chunk flush: coalesced write of CHUNK*128 floats (512 thr x float2)
            {
                float2 v = *reinterpret_cast<const float2*>(&hist[tid * 2]);
                *reinterpret_cast<float2*>(&seq_o[(size_t)t0 * HID + tid * 2]) = v;
            }
            __syncthreads();
            if (tid == 0)
                __hip_atomic_store(out_flag, c + 1, __ATOMIC_RELEASE, __HIP_MEMORY_SCOPE_AGENT);
        }
    } else {
        // ---------------- gi role: layer l (1..3), quad-owner, barrier-free steps ----------------
        float* auxg = smem;           // [CHUNK*HBUF] padded staged seq chunk
        const float* W   = WihR + (size_t)(l - 1) * G3 * HID;
        const float* seq_in = ws + GI_TOT + (size_t)(l - 1) * T_SEQ * HID;
        float* gi_o      = ws + (size_t)l * T_SEQ * G3;
        int* in_flag     = &fl[(4 + (l - 1)) * 16];
        int* out_flag    = &fl[l * 16];

        float w[3][32];
#pragma unroll
        for (int r = 0; r < 3; r++) {
            const float4* wr = reinterpret_cast<const float4*>(
                W + (size_t)(r * HID + j) * HID + kq * 32);
#pragma unroll
            for (int c = 0; c < 8; c++) {
                float4 v = wr[c];
                w[r][c * 4 + 0] = v.x; w[r][c * 4 + 1] = v.y;
                w[r][c * 4 + 2] = v.z; w[r][c * 4 + 3] = v.w;
            }
        }
        const float* bb = bih + (size_t)l * G3;
        float br = bb[j], bz = bb[HID + j], bn = bb[2 * HID + j];

        for (int c = 0; c < NCHUNK; c++) {
            if (tid == 0) {
                while (__hip_atomic_fetch_add(in_flag, 0, __ATOMIC_RELAXED, __HIP_MEMORY_SCOPE_AGENT) < c + 1)
                    __builtin_amdgcn_s_sleep(2);
            }
            __syncthreads();
            int t0 = c * CHUNK;
            // stage seq chunk into padded layout: 2 scalar writes/thread
#pragma unroll
            for (int k = tid; k < CHUNK * HID; k += 512) {
                int s  = k >> 7;
                int m  = k & 127;
                auxg[s * HBUF + (m >> 5) * SEGSTRIDE + (m & 31)] = seq_in[(size_t)t0 * HID + k];
            }
            __syncthreads();
            for (int s = 0; s < CHUNK; s++) {   // no per-step barrier: steps independent
                int t = t0 + s;
                const float4* h4 = reinterpret_cast<const float4*>(
                    auxg + s * HBUF + kq * SEGSTRIDE);
                float ar = 0.f, az = 0.f, an = 0.f;
#pragma unroll
                for (int cc = 0; cc < 8; cc++) {
                    float4 hv = h4[cc];
                    ar += w[0][cc*4+0]*hv.x + w[0][cc*4+1]*hv.y + w[0][cc*4+2]*hv.z + w[0][cc*4+3]*hv.w;
                    az += w[1][cc*4+0]*hv.x + w[1][cc*4+1]*hv.y + w[1][cc*4+2]*hv.z + w[1][cc*4+3]*hv.w;
                    an += w[2][cc*4+0]*hv.x + w[2][cc*4+1]*hv.y + w[2][cc*4+2]*hv.z + w[2][cc*4+3]*hv.w;
                }
                ar += __shfl_xor(ar, 1, 64);  az += __shfl_xor(az, 1, 64);  an += __shfl_xor(an, 1, 64);
                ar += __shfl_xor(ar, 2, 64);  az += __shfl_xor(az, 2, 64);  an += __shfl_xor(an, 2, 64);
                if (kq < 3) {
                    float val = (kq == 0) ? (ar + br) : (kq == 1) ? (az + bz) : (an + bn);
                    gi_o[(size_t)t * G3 + kq * HID + j] = val;
                }
            }
            __syncthreads();   // drains global stores of all threads into L2
            if (tid == 0)
                __hip_atomic_store(out_flag, c + 1, __ATOMIC_RELEASE, __HIP_MEMORY_SCOPE_AGENT);
        }
    }
}

// ---------------- FC head ----------------
__global__ void fc_kernel(const float* __restrict__ seq, const float* __restrict__ fc1w,
                          const float* __restrict__ fc1b, const float* __restrict__ fc2w,
                          const float* __restrict__ fc2b, float* __restrict__ out) {
    __shared__ float h3[HID];
    __shared__ float hid[HID];
    int t = blockIdx.x;
    int i = threadIdx.x;
    h3[i] = seq[t * HID + i];
    __syncthreads();
    const float4* w4 = reinterpret_cast<const float4*>(fc1w + i * HID);
    const float4* h4 = reinterpret_cast<const float4*>(h3);
    float a0 = 0.f, a1 = 0.f, a2 = 0.f, a3 = 0.f;
#pragma unroll
    for (int k = 0; k < 32; k += 4) {
        float4 w0 = w4[k], w1 = w4[k + 1], w2 = w4[k + 2], w3 = w4[k + 3];
        float4 h0 = h4[k], h1 = h4[k + 1], h2 = h4[k + 2], h3v = h4[k + 3];
        a0 += w0.x * h0.x + w0.y * h0.y + w0.z * h0.z + w0.w * h0.w;
        a1 += w1.x * h1.x + w1.y * h1.y + w1.z * h1.z + w1.w * h1.w;
        a2 += w2.x * h2.x + w2.y * h2.y + w2.z * h2.z + w2.w * h2.w;
        a3 += w3.x * h3v.x + w3.y * h3v.y + w3.z * h3v.z + w3.w * h3v.w;
    }
    float v = fc1b[i] + ((a0 + a1) + (a2 + a3));
    hid[i] = v > 0.0f ? v : 0.0f;
    __syncthreads();
    if (i < 3) {
        const float* w = fc2w + i * HID;
        float s = 0.f;
#pragma unroll
        for (int k = 0; k < HID; k++) s += w[k] * hid[k];
        out[t * 3 + i] = fc2b[i] + s;
    }
}

extern "C" void kernel_launch(void* const* d_in, const int* in_sizes, int n_in,
                              void* d_out, int out_size, void* d_ws, size_t ws_size,
                              hipStream_t stream) {
    const float* x     = (const float*)d_in[0];
    const float* Wih0  = (const float*)d_in[1];
    const float* WihR  = (const float*)d_in[2];   // (3, 384, 128)
    const float* Whh   = (const float*)d_in[3];   // (4, 384, 128)
    const float* bih   = (const float*)d_in[4];   // (4, 384)
    const float* bhh   = (const float*)d_in[5];   // (4, 384)
    const float* fc1w  = (const float*)d_in[6];
    const float* fc1b  = (const float*)d_in[7];
    const float* fc2w  = (const float*)d_in[8];
    const float* fc2b  = (const float*)d_in[9];
    float* out = (float*)d_out;
    float* ws  = (float*)d_ws;

    int*   flags = (int*)(ws + FLAG_OFF);
    float* gi0   = ws;
    float* seq3  = ws + GI_TOT + (size_t)3 * T_SEQ * HID;

    init_flags<<<1, 64, 0, stream>>>(flags);
    gi0_kernel<<<T_SEQ, G3, 0, stream>>>(x, Wih0, bih, gi0);
    pipe_kernel<<<7, 512, 0, stream>>>(ws, WihR, bih, Whh, bhh);
    fc_kernel<<<T_SEQ, HID, 0, stream>>>(seq3, fc1w, fc1b, fc2w, fc2b, out);
}

// Round 10
// 454.608 us; speedup vs baseline: 1.1757x; 1.1757x over previous
//
#include <hip/hip_runtime.h>
#include <math.h>

#define T_SEQ  512
#define HID    128
#define G3     384   // 3*HID, gate order r,z,n
#define NL     4
#define CHUNK  8
#define NCHUNK (T_SEQ / CHUNK)   // 64

// workspace layout (float offsets)
#define GI_TOT   (NL * T_SEQ * G3)
#define SEQ_TOT  (NL * T_SEQ * HID)
#define FLAG_OFF (GI_TOT + SEQ_TOT)

__device__ __forceinline__ float fsig(float x) {
    float e = __expf(-x);
    return 1.0f / (1.0f + e);
}
__device__ __forceinline__ float ftanh(float x) {
    float ax = fabsf(x);
    float e = __expf(-2.0f * ax);
    float t = (1.0f - e) / (1.0f + e);
    return copysignf(t, x);
}

// Handoff protocol (invalidate-free, stale-proof):
//  - writer: normal stores; __syncthreads(); RELEASE agent atomic flag store.
//  - reader: spins with RELAXED agent atomic fetch_add(0). RMW executes at the
//    coherence point every poll: no buffer_inv (R4-R6: 5.5x refetch from ACQUIRE),
//    no stale-cached-line stall (R8: 35 ms outlier from plain relaxed load).

// ---------------- init: reset handoff flags ----------------
__global__ void init_flags(int* fl) {
    int i = threadIdx.x;
    if (i < 8) fl[i * 16] = (i == 0) ? NCHUNK : 0;  // gi0 fully ready
}

// ---------------- layer-0 gi ----------------
__global__ void gi0_kernel(const float* __restrict__ x, const float* __restrict__ Wih0,
                           const float* __restrict__ bih, float* __restrict__ gi) {
    int t = blockIdx.x;
    int g = threadIdx.x;
    float x0 = x[t * 2048 + 1023];
    float x1 = x[t * 2048 + 1024 + 1023];
    gi[t * G3 + g] = bih[g] + Wih0[g * 2 + 0] * x0 + Wih0[g * 2 + 1] * x1;
}

// Packed inner product fragment: acc pair via float2 (compiler -> v_pk_fma_f32).
// s0,s1 are float2 accumulators; w2/h2 are float2 views of 32-float segments.
#define PK_DOT16(S0, S1, W2, H2)                    \
    _Pragma("unroll")                               \
    for (int pc = 0; pc < 16; pc += 2) {            \
        S0 += W2[pc]     * H2[pc];                  \
        S1 += W2[pc + 1] * H2[pc + 1];              \
    }

// ---------------- persistent pipeline: 7 blocks x 256 threads (R4 structure) ----------------
// bid 0,2,4,6 -> rec layer bid/2 ; bid 1,3,5 -> gi layer (bid+1)/2
// Decomposition: wave q = K-quarter [q*32,+32); lane rg owns rows rg*6..+5.
// R=6 rows/thread -> 32 ds_read_b128/step on the DS pipe (the binding pipe;
// 192/R rule: R9's R=3 doubled this and regressed).
__global__ __launch_bounds__(256, 1) void pipe_kernel(float* __restrict__ ws,
                                                      const float* __restrict__ WihR,
                                                      const float* __restrict__ bih,
                                                      const float* __restrict__ Whh,
                                                      const float* __restrict__ bhh) {
    __shared__ float smem[2688];
    float* h_s  = smem;          // [128]   (rec)
    float* ps   = smem + 128;    // [1536]  (both)
    float* aux  = smem + 1664;   // [1024]  hist (rec) / xs (gi)

    int bid = blockIdx.x;
    int tid = threadIdx.x;
    int q   = tid >> 6;          // wave = K-quarter
    int rg  = tid & 63;
    int row0 = rg * 6;
    int* fl = (int*)(ws + FLAG_OFF);
    bool is_rec = (bid & 1) == 0;
    int  l      = is_rec ? (bid >> 1) : ((bid + 1) >> 1);

    if (is_rec) {
        // ---------------- rec role: layer l ----------------
        const float* W   = Whh + (size_t)l * G3 * HID;
        const float* gi  = ws + (size_t)l * T_SEQ * G3;
        float* seq_o     = ws + GI_TOT + (size_t)l * T_SEQ * HID;
        int* in_flag     = &fl[l * 16];            // gi_l chunks ready
        int* out_flag    = &fl[(4 + l) * 16];      // seq_l chunks ready

        float w[6][32];
        const float* wbase = W + q * 32;
#pragma unroll
        for (int i = 0; i < 6; i++) {
            const float4* wr = reinterpret_cast<const float4*>(wbase + (size_t)(row0 + i) * HID);
#pragma unroll
            for (int c = 0; c < 8; c++) {
                float4 v = wr[c];
                w[i][c * 4 + 0] = v.x; w[i][c * 4 + 1] = v.y;
                w[i][c * 4 + 2] = v.z; w[i][c * 4 + 3] = v.w;
            }
        }

        float hprev = 0.f, br = 0.f, bz = 0.f, bn = 0.f;
        float gir = 0.f, giz = 0.f, gin = 0.f;
        float n_gir = 0.f, n_giz = 0.f, n_gin = 0.f;
        if (tid < HID) {
            h_s[tid] = 0.0f;
            const float* bb = bhh + (size_t)l * G3;
            br = bb[tid]; bz = bb[HID + tid]; bn = bb[2 * HID + tid];
        }
        __syncthreads();

        for (int c = 0; c < NCHUNK; c++) {
            if (tid == 0) {
                while (__hip_atomic_fetch_add(in_flag, 0, __ATOMIC_RELAXED, __HIP_MEMORY_SCOPE_AGENT) < c + 1)
                    __builtin_amdgcn_s_sleep(2);
            }
            __syncthreads();
            int t0 = c * CHUNK;
            if (tid < HID) {  // first-step gi load (once per chunk)
                const float* gp = gi + (size_t)t0 * G3;
                gir = gp[tid]; giz = gp[HID + tid]; gin = gp[2 * HID + tid];
            }
            for (int s = 0; s < CHUNK; s++) {
                int t = t0 + s;
                // issue next-step gi prefetch early (hides under matvec)
                if (tid < HID && s + 1 < CHUNK) {
                    const float* gp = gi + (size_t)(t + 1) * G3;
                    n_gir = gp[tid]; n_giz = gp[HID + tid]; n_gin = gp[2 * HID + tid];
                }
                // phase 1: partial matvec (packed fp32)
                const float4* h4 = reinterpret_cast<const float4*>(h_s + q * 32);
                float4 hv[8];
#pragma unroll
                for (int cc = 0; cc < 8; cc++) hv[cc] = h4[cc];
                const float2* h2 = reinterpret_cast<const float2*>(hv);
                float acc[6];
#pragma unroll
                for (int i = 0; i < 6; i++) {
                    const float2* w2 = reinterpret_cast<const float2*>(w[i]);
                    float2 s0 = {0.f, 0.f}, s1 = {0.f, 0.f};
                    PK_DOT16(s0, s1, w2, h2);
                    acc[i] = (s0.x + s0.y) + (s1.x + s1.y);
                }
#pragma unroll
                for (int i = 0; i < 6; i += 2) {
                    float2 p; p.x = acc[i]; p.y = acc[i + 1];
                    *reinterpret_cast<float2*>(&ps[q * G3 + row0 + i]) = p;
                }
                __syncthreads();
                // phase 2: reduce + gates
                if (tid < HID) {
                    int j = tid;
                    float ghr = (ps[j]         + ps[G3 + j])         + (ps[2*G3 + j]         + ps[3*G3 + j]);
                    float ghz = (ps[HID + j]   + ps[G3 + HID + j])   + (ps[2*G3 + HID + j]   + ps[3*G3 + HID + j]);
                    float ghn = (ps[2*HID + j] + ps[G3 + 2*HID + j]) + (ps[2*G3 + 2*HID + j] + ps[3*G3 + 2*HID + j]);
                    float r = fsig(gir + ghr + br);
                    float z = fsig(giz + ghz + bz);
                    float n = ftanh(gin + r * (ghn + bn));
                    float hn = (1.0f - z) * n + z * hprev;
                    hprev = hn;
                    h_s[j] = hn;
                    aux[s * HID + j] = hn;   // history in LDS, flushed per chunk
                    gir = n_gir; giz = n_giz; gin = n_gin;
                }
                __syncthreads();
            }
            // chunk flush: coalesced global write of CHUNK*128 floats
            {
                float4 v = *reinterpret_cast<const float4*>(&aux[tid * 4]);
                *reinterpret_cast<float4*>(&seq_o[(size_t)t0 * HID + tid * 4]) = v;
            }
            __syncthreads();
            if (tid == 0)
                __hip_atomic_store(out_flag, c + 1, __ATOMIC_RELEASE, __HIP_MEMORY_SCOPE_AGENT);
        }
    } else {
        // ---------------- gi role: layer l (1..3) ----------------
        const float* W   = WihR + (size_t)(l - 1) * G3 * HID;
        const float* seq_in = ws + GI_TOT + (size_t)(l - 1) * T_SEQ * HID;
        float* gi_o      = ws + (size_t)l * T_SEQ * G3;
        int* in_flag     = &fl[(4 + (l - 1)) * 16];   // seq_{l-1}
        int* out_flag    = &fl[l * 16];               // gi_l

        float w[6][32];
        const float* wbase = W + q * 32;
#pragma unroll
        for (int i = 0; i < 6; i++) {
            const float4* wr = reinterpret_cast<const float4*>(wbase + (size_t)(row0 + i) * HID);
#pragma unroll
            for (int c = 0; c < 8; c++) {
                float4 v = wr[c];
                w[i][c * 4 + 0] = v.x; w[i][c * 4 + 1] = v.y;
                w[i][c * 4 + 2] = v.z; w[i][c * 4 + 3] = v.w;
            }
        }
        float br = 0.f, bz = 0.f, bn = 0.f;
        if (tid < HID) {
            const float* bb = bih + (size_t)l * G3;
            br = bb[tid]; bz = bb[HID + tid]; bn = bb[2 * HID + tid];
        }

        for (int c = 0; c < NCHUNK; c++) {
            if (tid == 0) {
                while (__hip_atomic_fetch_add(in_flag, 0, __ATOMIC_RELAXED, __HIP_MEMORY_SCOPE_AGENT) < c + 1)
                    __builtin_amdgcn_s_sleep(2);
            }
            __syncthreads();
            int t0 = c * CHUNK;
            // stage seq chunk (1024 floats) into aux: one float4 per thread
            {
                float4 v = *reinterpret_cast<const float4*>(&seq_in[(size_t)t0 * HID + tid * 4]);
                *reinterpret_cast<float4*>(&aux[tid * 4]) = v;
            }
            __syncthreads();
            for (int s = 0; s < CHUNK; s++) {
                int t = t0 + s;
                const float4* h4 = reinterpret_cast<const float4*>(aux + s * HID + q * 32);
                float4 hv[8];
#pragma unroll
                for (int cc = 0; cc < 8; cc++) hv[cc] = h4[cc];
                const float2* h2 = reinterpret_cast<const float2*>(hv);
                float acc[6];
#pragma unroll
                for (int i = 0; i < 6; i++) {
                    const float2* w2 = reinterpret_cast<const float2*>(w[i]);
                    float2 s0 = {0.f, 0.f}, s1 = {0.f, 0.f};
                    PK_DOT16(s0, s1, w2, h2);
                    acc[i] = (s0.x + s0.y) + (s1.x + s1.y);
                }
#pragma unroll
                for (int i = 0; i < 6; i += 2) {
                    float2 p; p.x = acc[i]; p.y = acc[i + 1];
                    *reinterpret_cast<float2*>(&ps[q * G3 + row0 + i]) = p;
                }
                __syncthreads();
                if (tid < HID) {
                    int j = tid;
                    float vr = (ps[j]         + ps[G3 + j])         + (ps[2*G3 + j]         + ps[3*G3 + j]);
                    float vz = (ps[HID + j]   + ps[G3 + HID + j])   + (ps[2*G3 + HID + j]   + ps[3*G3 + HID + j]);
                    float vn = (ps[2*HID + j] + ps[G3 + 2*HID + j]) + (ps[2*G3 + 2*HID + j] + ps[3*G3 + 2*HID + j]);
                    float* gp = gi_o + (size_t)t * G3;
                    gp[j]           = vr + br;
                    gp[HID + j]     = vz + bz;
                    gp[2 * HID + j] = vn + bn;
                }
                __syncthreads();
            }
            __syncthreads();
            if (tid == 0)
                __hip_atomic_store(out_flag, c + 1, __ATOMIC_RELEASE, __HIP_MEMORY_SCOPE_AGENT);
        }
    }
}

// ---------------- FC head ----------------
__global__ void fc_kernel(const float* __restrict__ seq, const float* __restrict__ fc1w,
                          const float* __restrict__ fc1b, const float* __restrict__ fc2w,
                          const float* __restrict__ fc2b, float* __restrict__ out) {
    __shared__ float h3[HID];
    __shared__ float hid[HID];
    int t = blockIdx.x;
    int i = threadIdx.x;
    h3[i] = seq[t * HID + i];
    __syncthreads();
    const float4* w4 = reinterpret_cast<const float4*>(fc1w + i * HID);
    const float4* h4 = reinterpret_cast<const float4*>(h3);
    float a0 = 0.f, a1 = 0.f, a2 = 0.f, a3 = 0.f;
#pragma unroll
    for (int k = 0; k < 32; k += 4) {
        float4 w0 = w4[k], w1 = w4[k + 1], w2 = w4[k + 2], w3 = w4[k + 3];
        float4 h0 = h4[k], h1 = h4[k + 1], h2 = h4[k + 2], h3v = h4[k + 3];
        a0 += w0.x * h0.x + w0.y * h0.y + w0.z * h0.z + w0.w * h0.w;
        a1 += w1.x * h1.x + w1.y * h1.y + w1.z * h1.z + w1.w * h1.w;
        a2 += w2.x * h2.x + w2.y * h2.y + w2.z * h2.z + w2.w * h2.w;
        a3 += w3.x * h3v.x + w3.y * h3v.y + w3.z * h3v.z + w3.w * h3v.w;
    }
    float v = fc1b[i] + ((a0 + a1) + (a2 + a3));
    hid[i] = v > 0.0f ? v : 0.0f;
    __syncthreads();
    if (i < 3) {
        const float* w = fc2w + i * HID;
        float s = 0.f;
#pragma unroll
        for (int k = 0; k < HID; k++) s += w[k] * hid[k];
        out[t * 3 + i] = fc2b[i] + s;
    }
}

extern "C" void kernel_launch(void* const* d_in, const int* in_sizes, int n_in,
                              void* d_out, int out_size, void* d_ws, size_t ws_size,
                              hipStream_t stream) {
    const float* x     = (const float*)d_in[0];
    const float* Wih0  = (const float*)d_in[1];
    const float* WihR  = (const float*)d_in[2];   // (3, 384, 128)
    const float* Whh   = (const float*)d_in[3];   // (4, 384, 128)
    const float* bih   = (const float*)d_in[4];   // (4, 384)
    const float* bhh   = (const float*)d_in[5];   // (4, 384)
    const float* fc1w  = (const float*)d_in[6];
    const float* fc1b  = (const float*)d_in[7];
    const float* fc2w  = (const float*)d_in[8];
    const float* fc2b  = (const float*)d_in[9];
    float* out = (float*)d_out;
    float* ws  = (float*)d_ws;

    int*   flags = (int*)(ws + FLAG_OFF);
    float* gi0   = ws;
    float* seq3  = ws + GI_TOT + (size_t)3 * T_SEQ * HID;

    init_flags<<<1, 64, 0, stream>>>(flags);
    gi0_kernel<<<T_SEQ, G3, 0, stream>>>(x, Wih0, bih, gi0);
    pipe_kernel<<<7, 256, 0, stream>>>(ws, WihR, bih, Whh, bhh);
    fc_kernel<<<T_SEQ, HID, 0, stream>>>(seq3, fc1w, fc1b, fc2w, fc2b, out);
}

// Round 11
// 427.720 us; speedup vs baseline: 1.2496x; 1.0629x over previous
//
#include <hip/hip_runtime.h>
#include <math.h>

#define T_SEQ  512
#define HID    128
#define G3     384   // 3*HID, gate order r,z,n
#define NL     4
#define CHUNK  8
#define NCHUNK (T_SEQ / CHUNK)   // 64

// workspace layout (float offsets)
#define GI_TOT   (NL * T_SEQ * G3)
#define SEQ_TOT  (NL * T_SEQ * HID)
#define FLAG_OFF (GI_TOT + SEQ_TOT)

__device__ __forceinline__ float fsig(float x) {
    float e = __expf(-x);
    return 1.0f / (1.0f + e);
}
__device__ __forceinline__ float ftanh(float x) {
    float ax = fabsf(x);
    float e = __expf(-2.0f * ax);
    float t = (1.0f - e) / (1.0f + e);
    return copysignf(t, x);
}

// Handoff protocol (invalidate-free, stale-proof): writer = stores;
// __syncthreads (per-thread vmcnt drain -> L2); RELEASE agent flag store.
// Reader spins on RELAXED fetch_add(0) (RMW at coherence point: no buffer_inv,
// no stale line). Proven R8/R10.
//
// Barrier-drain rule (this round's lever): __syncthreads waits vmcnt(0), so ANY
// global op inside the per-step loop stalls the step's barrier by LLC latency.
// Keep the 8-step inner loops free of global loads/stores; do chunk-granular
// register staging instead.

// ---------------- init: reset handoff flags ----------------
__global__ void init_flags(int* fl) {
    int i = threadIdx.x;
    if (i < 8) fl[i * 16] = (i == 0) ? NCHUNK : 0;  // gi0 fully ready
}

// ---------------- layer-0 gi ----------------
__global__ void gi0_kernel(const float* __restrict__ x, const float* __restrict__ Wih0,
                           const float* __restrict__ bih, float* __restrict__ gi) {
    int t = blockIdx.x;
    int g = threadIdx.x;
    float x0 = x[t * 2048 + 1023];
    float x1 = x[t * 2048 + 1024 + 1023];
    gi[t * G3 + g] = bih[g] + Wih0[g * 2 + 0] * x0 + Wih0[g * 2 + 1] * x1;
}

// Packed inner product fragment (compiler -> v_pk_fma_f32).
#define PK_DOT16(S0, S1, W2, H2)                    \
    _Pragma("unroll")                               \
    for (int pc = 0; pc < 16; pc += 2) {            \
        S0 += W2[pc]     * H2[pc];                  \
        S1 += W2[pc + 1] * H2[pc + 1];              \
    }

// ---------------- persistent pipeline: 7 blocks x 256 threads (R4 structure) ----------------
// bid 0,2,4,6 -> rec layer bid/2 ; bid 1,3,5 -> gi layer (bid+1)/2
// Decomposition: wave q = K-quarter [q*32,+32); lane rg owns rows rg*6..+5.
__global__ __launch_bounds__(256, 1) void pipe_kernel(float* __restrict__ ws,
                                                      const float* __restrict__ WihR,
                                                      const float* __restrict__ bih,
                                                      const float* __restrict__ Whh,
                                                      const float* __restrict__ bhh) {
    __shared__ float smem[2688];
    float* h_s  = smem;          // [128]   (rec)
    float* ps   = smem + 128;    // [1536]  (both)
    float* aux  = smem + 1664;   // [1024]  hist (rec) / xs (gi)

    int bid = blockIdx.x;
    int tid = threadIdx.x;
    int q   = tid >> 6;          // wave = K-quarter
    int rg  = tid & 63;
    int row0 = rg * 6;
    int* fl = (int*)(ws + FLAG_OFF);
    bool is_rec = (bid & 1) == 0;
    int  l      = is_rec ? (bid >> 1) : ((bid + 1) >> 1);

    if (is_rec) {
        // ---------------- rec role: layer l ----------------
        const float* W   = Whh + (size_t)l * G3 * HID;
        const float* gi  = ws + (size_t)l * T_SEQ * G3;
        float* seq_o     = ws + GI_TOT + (size_t)l * T_SEQ * HID;
        int* in_flag     = &fl[l * 16];            // gi_l chunks ready
        int* out_flag    = &fl[(4 + l) * 16];      // seq_l chunks ready

        float w[6][32];
        const float* wbase = W + q * 32;
#pragma unroll
        for (int i = 0; i < 6; i++) {
            const float4* wr = reinterpret_cast<const float4*>(wbase + (size_t)(row0 + i) * HID);
#pragma unroll
            for (int c = 0; c < 8; c++) {
                float4 v = wr[c];
                w[i][c * 4 + 0] = v.x; w[i][c * 4 + 1] = v.y;
                w[i][c * 4 + 2] = v.z; w[i][c * 4 + 3] = v.w;
            }
        }

        float hprev = 0.f, br = 0.f, bz = 0.f, bn = 0.f;
        float g_r[CHUNK], g_z[CHUNK], g_n[CHUNK];   // chunk-staged gi (registers)
        if (tid < HID) {
            h_s[tid] = 0.0f;
            const float* bb = bhh + (size_t)l * G3;
            br = bb[tid]; bz = bb[HID + tid]; bn = bb[2 * HID + tid];
        }
        __syncthreads();

        for (int c = 0; c < NCHUNK; c++) {
            if (tid == 0) {
                while (__hip_atomic_fetch_add(in_flag, 0, __ATOMIC_RELAXED, __HIP_MEMORY_SCOPE_AGENT) < c + 1)
                    __builtin_amdgcn_s_sleep(2);
            }
            __syncthreads();
            int t0 = c * CHUNK;
            // chunk-granular gi stage into registers: drained ONCE at the first
            // step barrier instead of every step.
            if (tid < HID) {
                const float* gp = gi + (size_t)t0 * G3 + tid;
#pragma unroll
                for (int s = 0; s < CHUNK; s++) {
                    g_r[s] = gp[s * G3];
                    g_z[s] = gp[s * G3 + HID];
                    g_n[s] = gp[s * G3 + 2 * HID];
                }
            }
#pragma unroll
            for (int s = 0; s < CHUNK; s++) {
                // phase 1: partial matvec (packed fp32); no global ops in-loop
                const float4* h4 = reinterpret_cast<const float4*>(h_s + q * 32);
                float4 hv[8];
#pragma unroll
                for (int cc = 0; cc < 8; cc++) hv[cc] = h4[cc];
                const float2* h2 = reinterpret_cast<const float2*>(hv);
                float acc[6];
#pragma unroll
                for (int i = 0; i < 6; i++) {
                    const float2* w2 = reinterpret_cast<const float2*>(w[i]);
                    float2 s0 = {0.f, 0.f}, s1 = {0.f, 0.f};
                    PK_DOT16(s0, s1, w2, h2);
                    acc[i] = (s0.x + s0.y) + (s1.x + s1.y);
                }
#pragma unroll
                for (int i = 0; i < 6; i += 2) {
                    float2 p; p.x = acc[i]; p.y = acc[i + 1];
                    *reinterpret_cast<float2*>(&ps[q * G3 + row0 + i]) = p;
                }
                __syncthreads();
                // phase 2: reduce + gates
                if (tid < HID) {
                    int j = tid;
                    float ghr = (ps[j]         + ps[G3 + j])         + (ps[2*G3 + j]         + ps[3*G3 + j]);
                    float ghz = (ps[HID + j]   + ps[G3 + HID + j])   + (ps[2*G3 + HID + j]   + ps[3*G3 + HID + j]);
                    float ghn = (ps[2*HID + j] + ps[G3 + 2*HID + j]) + (ps[2*G3 + 2*HID + j] + ps[3*G3 + 2*HID + j]);
                    float r = fsig(g_r[s] + ghr + br);
                    float z = fsig(g_z[s] + ghz + bz);
                    float n = ftanh(g_n[s] + r * (ghn + bn));
                    float hn = (1.0f - z) * n + z * hprev;
                    hprev = hn;
                    h_s[j] = hn;
                    aux[s * HID + j] = hn;   // history in LDS, flushed per chunk
                }
                __syncthreads();
            }
            // chunk flush: coalesced global write of CHUNK*128 floats
            {
                float4 v = *reinterpret_cast<const float4*>(&aux[tid * 4]);
                *reinterpret_cast<float4*>(&seq_o[(size_t)t0 * HID + tid * 4]) = v;
            }
            __syncthreads();
            if (tid == 0)
                __hip_atomic_store(out_flag, c + 1, __ATOMIC_RELEASE, __HIP_MEMORY_SCOPE_AGENT);
        }
    } else {
        // ---------------- gi role: layer l (1..3) ----------------
        const float* W   = WihR + (size_t)(l - 1) * G3 * HID;
        const float* seq_in = ws + GI_TOT + (size_t)(l - 1) * T_SEQ * HID;
        float* gi_o      = ws + (size_t)l * T_SEQ * G3;
        int* in_flag     = &fl[(4 + (l - 1)) * 16];   // seq_{l-1}
        int* out_flag    = &fl[l * 16];               // gi_l

        float w[6][32];
        const float* wbase = W + q * 32;
#pragma unroll
        for (int i = 0; i < 6; i++) {
            const float4* wr = reinterpret_cast<const float4*>(wbase + (size_t)(row0 + i) * HID);
#pragma unroll
            for (int c = 0; c < 8; c++) {
                float4 v = wr[c];
                w[i][c * 4 + 0] = v.x; w[i][c * 4 + 1] = v.y;
                w[i][c * 4 + 2] = v.z; w[i][c * 4 + 3] = v.w;
            }
        }
        float br = 0.f, bz = 0.f, bn = 0.f;
        float o_r[CHUNK], o_z[CHUNK], o_n[CHUNK];   // chunk-accumulated outputs
        if (tid < HID) {
            const float* bb = bih + (size_t)l * G3;
            br = bb[tid]; bz = bb[HID + tid]; bn = bb[2 * HID + tid];
        }

        for (int c = 0; c < NCHUNK; c++) {
            if (tid == 0) {
                while (__hip_atomic_fetch_add(in_flag, 0, __ATOMIC_RELAXED, __HIP_MEMORY_SCOPE_AGENT) < c + 1)
                    __builtin_amdgcn_s_sleep(2);
            }
            __syncthreads();
            int t0 = c * CHUNK;
            // stage seq chunk (1024 floats) into aux: one float4 per thread
            {
                float4 v = *reinterpret_cast<const float4*>(&seq_in[(size_t)t0 * HID + tid * 4]);
                *reinterpret_cast<float4*>(&aux[tid * 4]) = v;
            }
            __syncthreads();
#pragma unroll
            for (int s = 0; s < CHUNK; s++) {
                const float4* h4 = reinterpret_cast<const float4*>(aux + s * HID + q * 32);
                float4 hv[8];
#pragma unroll
                for (int cc = 0; cc < 8; cc++) hv[cc] = h4[cc];
                const float2* h2 = reinterpret_cast<const float2*>(hv);
                float acc[6];
#pragma unroll
                for (int i = 0; i < 6; i++) {
                    const float2* w2 = reinterpret_cast<const float2*>(w[i]);
                    float2 s0 = {0.f, 0.f}, s1 = {0.f, 0.f};
                    PK_DOT16(s0, s1, w2, h2);
                    acc[i] = (s0.x + s0.y) + (s1.x + s1.y);
                }
#pragma unroll
                for (int i = 0; i < 6; i += 2) {
                    float2 p; p.x = acc[i]; p.y = acc[i + 1];
                    *reinterpret_cast<float2*>(&ps[q * G3 + row0 + i]) = p;
                }
                __syncthreads();
                // accumulate into registers; no global stores in-loop
                if (tid < HID) {
                    int j = tid;
                    o_r[s] = (ps[j]         + ps[G3 + j])         + (ps[2*G3 + j]         + ps[3*G3 + j]);
                    o_z[s] = (ps[HID + j]   + ps[G3 + HID + j])   + (ps[2*G3 + HID + j]   + ps[3*G3 + HID + j]);
                    o_n[s] = (ps[2*HID + j] + ps[G3 + 2*HID + j]) + (ps[2*G3 + 2*HID + j] + ps[3*G3 + 2*HID + j]);
                }
                __syncthreads();
            }
            // chunk flush: 24 coalesced stores, drained once at the sync below
            if (tid < HID) {
                int j = tid;
                float* gp = gi_o + (size_t)t0 * G3 + j;
#pragma unroll
                for (int s = 0; s < CHUNK; s++) {
                    gp[s * G3]           = o_r[s] + br;
                    gp[s * G3 + HID]     = o_z[s] + bz;
                    gp[s * G3 + 2 * HID] = o_n[s] + bn;
                }
            }
            __syncthreads();
            if (tid == 0)
                __hip_atomic_store(out_flag, c + 1, __ATOMIC_RELEASE, __HIP_MEMORY_SCOPE_AGENT);
        }
    }
}

// ---------------- FC head ----------------
__global__ void fc_kernel(const float* __restrict__ seq, const float* __restrict__ fc1w,
                          const float* __restrict__ fc1b, const float* __restrict__ fc2w,
                          const float* __restrict__ fc2b, float* __restrict__ out) {
    __shared__ float h3[HID];
    __shared__ float hid[HID];
    int t = blockIdx.x;
    int i = threadIdx.x;
    h3[i] = seq[t * HID + i];
    __syncthreads();
    const float4* w4 = reinterpret_cast<const float4*>(fc1w + i * HID);
    const float4* h4 = reinterpret_cast<const float4*>(h3);
    float a0 = 0.f, a1 = 0.f, a2 = 0.f, a3 = 0.f;
#pragma unroll
    for (int k = 0; k < 32; k += 4) {
        float4 w0 = w4[k], w1 = w4[k + 1], w2 = w4[k + 2], w3 = w4[k + 3];
        float4 h0 = h4[k], h1 = h4[k + 1], h2 = h4[k + 2], h3v = h4[k + 3];
        a0 += w0.x * h0.x + w0.y * h0.y + w0.z * h0.z + w0.w * h0.w;
        a1 += w1.x * h1.x + w1.y * h1.y + w1.z * h1.z + w1.w * h1.w;
        a2 += w2.x * h2.x + w2.y * h2.y + w2.z * h2.z + w2.w * h2.w;
        a3 += w3.x * h3v.x + w3.y * h3v.y + w3.z * h3v.z + w3.w * h3v.w;
    }
    float v = fc1b[i] + ((a0 + a1) + (a2 + a3));
    hid[i] = v > 0.0f ? v : 0.0f;
    __syncthreads();
    if (i < 3) {
        const float* w = fc2w + i * HID;
        float s = 0.f;
#pragma unroll
        for (int k = 0; k < HID; k++) s += w[k] * hid[k];
        out[t * 3 + i] = fc2b[i] + s;
    }
}

extern "C" void kernel_launch(void* const* d_in, const int* in_sizes, int n_in,
                              void* d_out, int out_size, void* d_ws, size_t ws_size,
                              hipStream_t stream) {
    const float* x     = (const float*)d_in[0];
    const float* Wih0  = (const float*)d_in[1];
    const float* WihR  = (const float*)d_in[2];   // (3, 384, 128)
    const float* Whh   = (const float*)d_in[3];   // (4, 384, 128)
    const float* bih   = (const float*)d_in[4];   // (4, 384)
    const float* bhh   = (const float*)d_in[5];   // (4, 384)
    const float* fc1w  = (const float*)d_in[6];
    const float* fc1b  = (const float*)d_in[7];
    const float* fc2w  = (const float*)d_in[8];
    const float* fc2b  = (const float*)d_in[9];
    float* out = (float*)d_out;
    float* ws  = (float*)d_ws;

    int*   flags = (int*)(ws + FLAG_OFF);
    float* gi0   = ws;
    float* seq3  = ws + GI_TOT + (size_t)3 * T_SEQ * HID;

    init_flags<<<1, 64, 0, stream>>>(flags);
    gi0_kernel<<<T_SEQ, G3, 0, stream>>>(x, Wih0, bih, gi0);
    pipe_kernel<<<7, 256, 0, stream>>>(ws, WihR, bih, Whh, bhh);
    fc_kernel<<<T_SEQ, HID, 0, stream>>>(seq3, fc1w, fc1b, fc2w, fc2b, out);
}

// Round 12
// 393.971 us; speedup vs baseline: 1.3567x; 1.0857x over previous
//
#include <hip/hip_runtime.h>
#include <math.h>

#define T_SEQ  512
#define HID    128
#define G3     384   // 3*HID, gate order r,z,n
#define NL     4
#define CHUNK  8
#define NCHUNK (T_SEQ / CHUNK)   // 64

// workspace layout (float offsets)
#define GI_TOT   (NL * T_SEQ * G3)
#define SEQ_TOT  (NL * T_SEQ * HID)
#define FLAG_OFF (GI_TOT + SEQ_TOT)

__device__ __forceinline__ float fsig(float x) {
    float e = __expf(-x);
    return 1.0f / (1.0f + e);
}
__device__ __forceinline__ float ftanh(float x) {
    float ax = fabsf(x);
    float e = __expf(-2.0f * ax);
    float t = (1.0f - e) / (1.0f + e);
    return copysignf(t, x);
}
// lane-register broadcast: VALU v_readlane_b32, stays off the DS pipe
__device__ __forceinline__ float rdlane(float v, int k) {
    return __uint_as_float(__builtin_amdgcn_readlane(__float_as_uint(v), k));
}

// Handoff protocol (invalidate-free, stale-proof): writer = stores;
// __syncthreads (per-thread vmcnt drain -> L2); RELEASE agent flag store.
// Reader spins on RELAXED fetch_add(0) (RMW at coherence point: no buffer_inv,
// no stale line). Proven R8/R10/R11.

// ---------------- init: reset handoff flags ----------------
__global__ void init_flags(int* fl) {
    int i = threadIdx.x;
    if (i < 8) fl[i * 16] = (i == 0) ? NCHUNK : 0;  // gi0 fully ready
}

// ---------------- layer-0 gi ----------------
__global__ void gi0_kernel(const float* __restrict__ x, const float* __restrict__ Wih0,
                           const float* __restrict__ bih, float* __restrict__ gi) {
    int t = blockIdx.x;
    int g = threadIdx.x;
    float x0 = x[t * 2048 + 1023];
    float x1 = x[t * 2048 + 1024 + 1023];
    gi[t * G3 + g] = bih[g] + Wih0[g * 2 + 0] * x0 + Wih0[g * 2 + 1] * x1;
}

// ---------------- persistent pipeline: 7 blocks x 256 threads ----------------
// bid 0,2,4,6 -> rec layer bid/2 ; bid 1,3,5 -> gi layer (bid+1)/2
// P1 decomposition (both roles): wave q owns K-quarter; lane rg rows rg*6..+5.
// rec: h broadcast via v_readlane from each wave's own P2 lanes (no LDS h),
// ps double-buffered -> ONE barrier/step. gi: 8 independent steps, big ps,
// ONE barrier/chunk, distributed reduce.
__global__ __launch_bounds__(256, 1) void pipe_kernel(float* __restrict__ ws,
                                                      const float* __restrict__ WihR,
                                                      const float* __restrict__ bih,
                                                      const float* __restrict__ Whh,
                                                      const float* __restrict__ bhh) {
    __shared__ float smem[12288];  // gi: ps_big[8][4][384]; rec: psdb[2][1536] + aux@3072

    int bid  = blockIdx.x;
    int tid  = threadIdx.x;
    int lane = tid & 63;
    int q    = tid >> 6;         // wave = K-quarter
    int row0 = lane * 6;
    int* fl = (int*)(ws + FLAG_OFF);
    bool is_rec = (bid & 1) == 0;
    int  l      = is_rec ? (bid >> 1) : ((bid + 1) >> 1);

    if (is_rec) {
        // ---------------- rec role: layer l ----------------
        const float* W   = Whh + (size_t)l * G3 * HID;
        const float* gi  = ws + (size_t)l * T_SEQ * G3;
        float* seq_o     = ws + GI_TOT + (size_t)l * T_SEQ * HID;
        float* aux       = smem + 3072;            // [1024] chunk history
        int* in_flag     = &fl[l * 16];
        int* out_flag    = &fl[(4 + l) * 16];

        float w[6][32];
        const float* wbase = W + q * 32;
#pragma unroll
        for (int i = 0; i < 6; i++) {
            const float4* wr = reinterpret_cast<const float4*>(wbase + (size_t)(row0 + i) * HID);
#pragma unroll
            for (int c = 0; c < 8; c++) {
                float4 v = wr[c];
                w[i][c * 4 + 0] = v.x; w[i][c * 4 + 1] = v.y;
                w[i][c * 4 + 2] = v.z; w[i][c * 4 + 3] = v.w;
            }
        }

        int  m  = lane & 31;
        bool p2 = (lane < 32);
        int  j  = q * 32 + m;          // this wave's P2 output index
        const float* bb = bhh + (size_t)l * G3;
        float br = 0.f, bz = 0.f, bn = 0.f;
        if (p2) { br = bb[j]; bz = bb[HID + j]; bn = bb[2 * HID + j]; }

        float hs[32];                  // wave-uniform h slice (this wave's K-quarter)
#pragma unroll
        for (int k = 0; k < 32; k++) hs[k] = 0.f;
        float hprev = 0.f;
        float g_r[CHUNK], g_z[CHUNK], g_n[CHUNK];

        for (int c = 0; c < NCHUNK; c++) {
            if (tid == 0) {
                while (__hip_atomic_fetch_add(in_flag, 0, __ATOMIC_RELAXED, __HIP_MEMORY_SCOPE_AGENT) < c + 1)
                    __builtin_amdgcn_s_sleep(2);
            }
            __syncthreads();
            int t0 = c * CHUNK;
            if (p2) {   // chunk-granular gi register stage (drained at first barrier)
                const float* gp = gi + (size_t)t0 * G3 + j;
#pragma unroll
                for (int s = 0; s < CHUNK; s++) {
                    g_r[s] = gp[s * G3];
                    g_z[s] = gp[s * G3 + HID];
                    g_n[s] = gp[s * G3 + 2 * HID];
                }
            }
#pragma unroll
            for (int s = 0; s < CHUNK; s++) {
                int t = t0 + s;
                float* psb = smem + (t & 1) * 1536;   // double-buffered partials
                // P1: matvec on wave-uniform hs (no LDS reads)
                float acc[6];
#pragma unroll
                for (int i = 0; i < 6; i++) {
                    float a0 = 0.f, a1 = 0.f, a2 = 0.f, a3 = 0.f;
#pragma unroll
                    for (int k = 0; k < 32; k += 4) {
                        a0 += w[i][k]     * hs[k];
                        a1 += w[i][k + 1] * hs[k + 1];
                        a2 += w[i][k + 2] * hs[k + 2];
                        a3 += w[i][k + 3] * hs[k + 3];
                    }
                    acc[i] = (a0 + a1) + (a2 + a3);
                }
#pragma unroll
                for (int i = 0; i < 6; i += 2) {
                    float2 p; p.x = acc[i]; p.y = acc[i + 1];
                    *reinterpret_cast<float2*>(&psb[q * G3 + row0 + i]) = p;
                }
                __syncthreads();   // the ONLY barrier per step
                // P2 (replicated per wave, lanes 0..31): this wave's h slice
                float hn_bc = 0.f;
                if (p2) {
                    float ghr = (psb[j]         + psb[G3 + j])         + (psb[2*G3 + j]         + psb[3*G3 + j]);
                    float ghz = (psb[HID + j]   + psb[G3 + HID + j])   + (psb[2*G3 + HID + j]   + psb[3*G3 + HID + j]);
                    float ghn = (psb[2*HID + j] + psb[G3 + 2*HID + j]) + (psb[2*G3 + 2*HID + j] + psb[3*G3 + 2*HID + j]);
                    float r = fsig(g_r[s] + ghr + br);
                    float z = fsig(g_z[s] + ghz + bz);
                    float n = ftanh(g_n[s] + r * (ghn + bn));
                    float hn = (1.0f - z) * n + z * hprev;
                    hprev = hn;
                    aux[s * HID + j] = hn;
                    hn_bc = hn;
                }
                // broadcast this wave's 32 new h values into uniform registers
#pragma unroll
                for (int k = 0; k < 32; k++) hs[k] = rdlane(hn_bc, k);
            }
            __syncthreads();   // aux complete before flush
            {   // chunk flush: coalesced write of CHUNK*128 floats
                float4 v = *reinterpret_cast<const float4*>(&aux[tid * 4]);
                *reinterpret_cast<float4*>(&seq_o[(size_t)t0 * HID + tid * 4]) = v;
            }
            __syncthreads();
            if (tid == 0)
                __hip_atomic_store(out_flag, c + 1, __ATOMIC_RELEASE, __HIP_MEMORY_SCOPE_AGENT);
        }
    } else {
        // ---------------- gi role: layer l (1..3) ----------------
        const float* W   = WihR + (size_t)(l - 1) * G3 * HID;
        const float* seq_in = ws + GI_TOT + (size_t)(l - 1) * T_SEQ * HID;
        float* gi_o      = ws + (size_t)l * T_SEQ * G3;
        int* in_flag     = &fl[(4 + (l - 1)) * 16];
        int* out_flag    = &fl[l * 16];

        float w[6][32];
        const float* wbase = W + q * 32;
#pragma unroll
        for (int i = 0; i < 6; i++) {
            const float4* wr = reinterpret_cast<const float4*>(wbase + (size_t)(row0 + i) * HID);
#pragma unroll
            for (int c = 0; c < 8; c++) {
                float4 v = wr[c];
                w[i][c * 4 + 0] = v.x; w[i][c * 4 + 1] = v.y;
                w[i][c * 4 + 2] = v.z; w[i][c * 4 + 3] = v.w;
            }
        }
        int m  = lane & 31;
        // reduce-phase ownership: step s2 = tid>>5, columns {m2, m2+32, m2+64, m2+96}
        int m2 = tid & 31;
        int s2 = tid >> 5;
        const float* bb = bih + (size_t)l * G3;
        float br4[4], bz4[4], bn4[4];
#pragma unroll
        for (int u = 0; u < 4; u++) {
            int jj = u * 32 + m2;
            br4[u] = bb[jj]; bz4[u] = bb[HID + jj]; bn4[u] = bb[2 * HID + jj];
        }

        for (int c = 0; c < NCHUNK; c++) {
            if (tid == 0) {
                while (__hip_atomic_fetch_add(in_flag, 0, __ATOMIC_RELAXED, __HIP_MEMORY_SCOPE_AGENT) < c + 1)
                    __builtin_amdgcn_s_sleep(2);
            }
            __syncthreads();
            int t0 = c * CHUNK;
            // seq chunk straight to lane registers (no LDS staging)
            float vseq[CHUNK];
            {
                const float* sp = seq_in + (size_t)t0 * HID + q * 32 + m;
#pragma unroll
                for (int s = 0; s < CHUNK; s++) vseq[s] = sp[s * HID];
            }
            // 8 independent matvec steps -> big ps, NO per-step barrier
#pragma unroll
            for (int s = 0; s < CHUNK; s++) {
                float xs[32];
#pragma unroll
                for (int k = 0; k < 32; k++) xs[k] = rdlane(vseq[s], k);
                float acc[6];
#pragma unroll
                for (int i = 0; i < 6; i++) {
                    float a0 = 0.f, a1 = 0.f, a2 = 0.f, a3 = 0.f;
#pragma unroll
                    for (int k = 0; k < 32; k += 4) {
                        a0 += w[i][k]     * xs[k];
                        a1 += w[i][k + 1] * xs[k + 1];
                        a2 += w[i][k + 2] * xs[k + 2];
                        a3 += w[i][k + 3] * xs[k + 3];
                    }
                    acc[i] = (a0 + a1) + (a2 + a3);
                }
                float* pp = smem + s * 1536;
#pragma unroll
                for (int i = 0; i < 6; i += 2) {
                    float2 p; p.x = acc[i]; p.y = acc[i + 1];
                    *reinterpret_cast<float2*>(&pp[q * G3 + row0 + i]) = p;
                }
            }
            __syncthreads();   // the ONE barrier per chunk
            // distributed reduce + biased store (thread: step s2, 4 columns)
#pragma unroll
            for (int u = 0; u < 4; u++) {
                int jj = u * 32 + m2;
                const float* pp = smem + s2 * 1536;
                float vr = (pp[jj]         + pp[G3 + jj])         + (pp[2*G3 + jj]         + pp[3*G3 + jj]);
                float vz = (pp[HID + jj]   + pp[G3 + HID + jj])   + (pp[2*G3 + HID + jj]   + pp[3*G3 + HID + jj]);
                float vn = (pp[2*HID + jj] + pp[G3 + 2*HID + jj]) + (pp[2*G3 + 2*HID + jj] + pp[3*G3 + 2*HID + jj]);
                float* gp = gi_o + (size_t)(t0 + s2) * G3;
                gp[jj]           = vr + br4[u];
                gp[HID + jj]     = vz + bz4[u];
                gp[2 * HID + jj] = vn + bn4[u];
            }
            __syncthreads();   // all gi stores drained before flag
            if (tid == 0)
                __hip_atomic_store(out_flag, c + 1, __ATOMIC_RELEASE, __HIP_MEMORY_SCOPE_AGENT);
        }
    }
}

// ---------------- FC head ----------------
__global__ void fc_kernel(const float* __restrict__ seq, const float* __restrict__ fc1w,
                          const float* __restrict__ fc1b, const float* __restrict__ fc2w,
                          const float* __restrict__ fc2b, float* __restrict__ out) {
    __shared__ float h3[HID];
    __shared__ float hid[HID];
    int t = blockIdx.x;
    int i = threadIdx.x;
    h3[i] = seq[t * HID + i];
    __syncthreads();
    const float4* w4 = reinterpret_cast<const float4*>(fc1w + i * HID);
    const float4* h4 = reinterpret_cast<const float4*>(h3);
    float a0 = 0.f, a1 = 0.f, a2 = 0.f, a3 = 0.f;
#pragma unroll
    for (int k = 0; k < 32; k += 4) {
        float4 w0 = w4[k], w1 = w4[k + 1], w2 = w4[k + 2], w3 = w4[k + 3];
        float4 h0 = h4[k], h1 = h4[k + 1], h2 = h4[k + 2], h3v = h4[k + 3];
        a0 += w0.x * h0.x + w0.y * h0.y + w0.z * h0.z + w0.w * h0.w;
        a1 += w1.x * h1.x + w1.y * h1.y + w1.z * h1.z + w1.w * h1.w;
        a2 += w2.x * h2.x + w2.y * h2.y + w2.z * h2.z + w2.w * h2.w;
        a3 += w3.x * h3v.x + w3.y * h3v.y + w3.z * h3v.z + w3.w * h3v.w;
    }
    float v = fc1b[i] + ((a0 + a1) + (a2 + a3));
    hid[i] = v > 0.0f ? v : 0.0f;
    __syncthreads();
    if (i < 3) {
        const float* w = fc2w + i * HID;
        float s = 0.f;
#pragma unroll
        for (int k = 0; k < HID; k++) s += w[k] * hid[k];
        out[t * 3 + i] = fc2b[i] + s;
    }
}

extern "C" void kernel_launch(void* const* d_in, const int* in_sizes, int n_in,
                              void* d_out, int out_size, void* d_ws, size_t ws_size,
                              hipStream_t stream) {
    const float* x     = (const float*)d_in[0];
    const float* Wih0  = (const float*)d_in[1];
    const float* WihR  = (const float*)d_in[2];   // (3, 384, 128)
    const float* Whh   = (const float*)d_in[3];   // (4, 384, 128)
    const float* bih   = (const float*)d_in[4];   // (4, 384)
    const float* bhh   = (const float*)d_in[5];   // (4, 384)
    const float* fc1w  = (const float*)d_in[6];
    const float* fc1b  = (const float*)d_in[7];
    const float* fc2w  = (const float*)d_in[8];
    const float* fc2b  = (const float*)d_in[9];
    float* out = (float*)d_out;
    float* ws  = (float*)d_ws;

    int*   flags = (int*)(ws + FLAG_OFF);
    float* gi0   = ws;
    float* seq3  = ws + GI_TOT + (size_t)3 * T_SEQ * HID;

    init_flags<<<1, 64, 0, stream>>>(flags);
    gi0_kernel<<<T_SEQ, G3, 0, stream>>>(x, Wih0, bih, gi0);
    pipe_kernel<<<7, 256, 0, stream>>>(ws, WihR, bih, Whh, bhh);
    fc_kernel<<<T_SEQ, HID, 0, stream>>>(seq3, fc1w, fc1b, fc2w, fc2b, out);
}